// Round 7
// baseline (230.258 us; speedup 1.0000x reference)
//
#include <hip/hip_runtime.h>
#include <hip/hip_bf16.h>
#include <math.h>

// ws layout (float slots)
#define OFF_XH   0UL         // bf16 x  (bh, l, 128)
#define OFF_XT   1572864UL   // bf16 x^T (bh, 128, l) token-paired u32
#define OFF_VC   3145728UL   // bf16 vc (b, l, 768)
#define OFF_SQ   4718592UL   // fp32 per-(bh,l) sumsq
#define OFF_THS  4743168UL   // fp32 per-(bh,l) sum
#define OFF_PART 4767744UL   // fp32 dist partials 96*16*2
#define OFF_STAT 4770816UL   // 24

typedef __attribute__((ext_vector_type(8))) __bf16 bf16x8;
typedef __attribute__((ext_vector_type(4))) float f32x4;
typedef __attribute__((ext_vector_type(8))) unsigned short u16x8;

// ---------------- K1: gather+scale -> xh AND xT + per-token stats ----------------
__global__ __launch_bounds__(256) void k1_gather(const int* __restrict__ tids,
    const float* __restrict__ TF, const float* __restrict__ DF,
    const float* __restrict__ emb, unsigned short* __restrict__ xh,
    unsigned short* __restrict__ xT, float* __restrict__ sq, float* __restrict__ ths) {
  int bh = blockIdx.x >> 4, tg = blockIdx.x & 15;
  int b = bh / 6, h = bh % 6;
  int T0 = tg * 16;
  int tid = threadIdx.x;
  __shared__ float swgt[16];
  __shared__ int stid[16];
  __shared__ unsigned short tT[128][18];
  if (tid < 16) {
    int tok = b * 256 + T0 + tid;
    stid[tid] = tids[tok];
    swgt[tid] = fminf(TF[tok], 20.0f) * log1pf(1.0f / DF[tok]);
  }
  __syncthreads();
  int r = tid >> 4, c8 = (tid & 15) * 8;
  const float* er = emb + (size_t)stid[r] * 768 + h * 128 + c8;
  float wgt = swgt[r];
  float4 e0 = *(const float4*)er;
  float4 e1 = *(const float4*)(er + 4);
  float f[8] = {e0.x, e0.y, e0.z, e0.w, e1.x, e1.y, e1.z, e1.w};
  float s1 = 0.0f, s2 = 0.0f;
  u16x8 pk;
#pragma unroll
  for (int e = 0; e < 8; ++e) {
    __hip_bfloat16 hb = __float2bfloat16(f[e] * wgt);
    float g = __bfloat162float(hb);
    s1 += g; s2 += g * g;
    pk[e] = __bfloat16_as_ushort(hb);
  }
  *(u16x8*)(xh + ((size_t)(bh * 256 + T0 + r)) * 128 + c8) = pk;
  s1 += __shfl_down(s1, 8); s1 += __shfl_down(s1, 4);
  s1 += __shfl_down(s1, 2); s1 += __shfl_down(s1, 1);
  s2 += __shfl_down(s2, 8); s2 += __shfl_down(s2, 4);
  s2 += __shfl_down(s2, 2); s2 += __shfl_down(s2, 1);
  if ((tid & 15) == 0) {
    ths[bh * 256 + T0 + r] = s1;
    sq[bh * 256 + T0 + r]  = s2;
  }
#pragma unroll
  for (int j = 0; j < 8; ++j) tT[c8 + j][r] = pk[j];
  __syncthreads();
  int ch = tid >> 1, half = tid & 1;
  unsigned int* xo = (unsigned int*)xT + ((size_t)(bh * 128 + ch)) * 128 + tg * 8 + half * 4;
#pragma unroll
  for (int k = 0; k < 4; ++k)
    xo[k] = *(const unsigned int*)&tT[ch][(half * 4 + k) * 2];
}

// ---------------- K2: distance-stat partials. 1 wave = 16 rows x 256 cols ----------------
__global__ __launch_bounds__(64) void k2_stats(const unsigned short* __restrict__ xh,
    const float* __restrict__ sq, float* __restrict__ part) {
  int p = blockIdx.x, bh = blockIdx.y;
  int lane = threadIdx.x;
  int quad = lane >> 4, l16 = lane & 15;
  int I = p * 16;
  const __bf16* xb = (const __bf16*)xh + (size_t)bh * 256 * 128;
  bf16x8 a[4];
#pragma unroll
  for (int k0 = 0; k0 < 4; ++k0)
    a[k0] = *(const bf16x8*)(xb + (size_t)(I + l16) * 128 + k0 * 32 + quad * 8);
  const float* sqh = sq + (size_t)bh * 256;
  float si[4];
#pragma unroll
  for (int r = 0; r < 4; ++r) si[r] = sqh[I + quad * 4 + r];
  float ls1 = 0.0f, ls2 = 0.0f;
#pragma unroll
  for (int t = 0; t < 16; ++t) {
    f32x4 acc = {0.0f, 0.0f, 0.0f, 0.0f};
#pragma unroll
    for (int k0 = 0; k0 < 4; ++k0) {
      bf16x8 bfr = *(const bf16x8*)(xb + (size_t)(t * 16 + l16) * 128 + k0 * 32 + quad * 8);
      acc = __builtin_amdgcn_mfma_f32_16x16x32_bf16(a[k0], bfr, acc, 0, 0, 0);
    }
    float sj = sqh[t * 16 + l16];
#pragma unroll
    for (int r = 0; r < 4; ++r) {
      float cv = sqrtf(fmaxf(si[r] + sj - 2.0f * acc[r], 1e-12f));
      ls1 += cv; ls2 += cv * cv;
    }
  }
#pragma unroll
  for (int off = 32; off >= 1; off >>= 1) {
    ls1 += __shfl_down(ls1, off);
    ls2 += __shfl_down(ls2, off);
  }
  if (lane == 0) {
    part[((size_t)bh * 16 + p) * 2 + 0] = ls1;
    part[((size_t)bh * 16 + p) * 2 + 1] = ls2;
  }
}

// ---------------- K3: finalize both BN stat sets ----------------
__global__ __launch_bounds__(384) void k3_stats(const float* __restrict__ ths,
    const float* __restrict__ sq, const float* __restrict__ part,
    float* __restrict__ stats) {
  int h = threadIdx.x >> 6, lane = threadIdx.x & 63;
  float s1 = 0.0f, s2 = 0.0f;
  for (int m = 0; m < 64; ++m) {
    int f = m * 64 + lane;
    int bb = f >> 8, l = f & 255;
    size_t idx = ((size_t)(bb * 6 + h)) * 256 + l;
    s1 += ths[idx]; s2 += sq[idx];
  }
#pragma unroll
  for (int off = 32; off >= 1; off >>= 1) {
    s1 += __shfl_down(s1, off);
    s2 += __shfl_down(s2, off);
  }
  if (lane == 0) {
    float cnt = 524288.0f;               // B*L*dh
    float mean = s1 / cnt;
    float var = s2 / cnt - mean * mean;
    stats[h] = mean;
    stats[6 + h] = rsqrtf(var + 1e-5f);
  }
  float c1 = 0.0f, c2 = 0.0f;
#pragma unroll
  for (int t = 0; t < 4; ++t) {
    int e = lane + 64 * t;               // 0..255 = 16 b x 16 p
    int bb = e >> 4, pp = e & 15;
    size_t pidx = ((size_t)(bb * 6 + h) * 16 + pp) * 2;
    c1 += part[pidx]; c2 += part[pidx + 1];
  }
#pragma unroll
  for (int off = 32; off >= 1; off >>= 1) {
    c1 += __shfl_down(c1, off);
    c2 += __shfl_down(c2, off);
  }
  if (lane == 0) {
    float cnt = 1048576.0f;              // B*L*L
    float mean = c1 / cnt;
    float var = c2 / cnt - mean * mean;
    stats[12 + h] = mean;
    stats[18 + h] = rsqrtf(var + 1e-5f);
  }
}

// ---------------- K45: dist + bn + leaky + mask + softmax (LDS co) + AV -> vc ----------------
// 1 wave = 16 output rows. co tile lives only in LDS ([16][264]: row shift 4 banks
// -> worst 2-way read conflict = free).
__global__ __launch_bounds__(64) void k45_fused(const unsigned short* __restrict__ xh,
    const unsigned short* __restrict__ xT, const int* __restrict__ tids,
    const float* __restrict__ sq, const float* __restrict__ stats,
    unsigned short* __restrict__ vc16) {
  int p = blockIdx.x, bh = blockIdx.y;
  int b = bh / 6, h = bh % 6;
  int lane = threadIdx.x;
  int quad = lane >> 4, l16 = lane & 15;
  int I = p * 16;
  __shared__ float svld[256];
  __shared__ float ssq[256];
  __shared__ unsigned short cot[16][264];
#pragma unroll
  for (int t = 0; t < 4; ++t) {
    int i = lane + 64 * t;
    svld[i] = (tids[b * 256 + i] != 0) ? 1.0f : 0.0f;
    ssq[i] = sq[(size_t)bh * 256 + i];
  }
  const __bf16* xb = (const __bf16*)xh + (size_t)bh * 256 * 128;
  bf16x8 a[4];
#pragma unroll
  for (int k0 = 0; k0 < 4; ++k0)
    a[k0] = *(const bf16x8*)(xb + (size_t)(I + l16) * 128 + k0 * 32 + quad * 8);
  __syncthreads();
  float m = stats[12 + h], rsc = stats[18 + h];
  float rv[4], si[4];
#pragma unroll
  for (int r = 0; r < 4; ++r) {
    rv[r] = svld[I + quad * 4 + r];
    si[r] = ssq[I + quad * 4 + r];
  }
  float y[16][4];
#pragma unroll
  for (int t = 0; t < 16; ++t) {
    f32x4 acc = {0.0f, 0.0f, 0.0f, 0.0f};
#pragma unroll
    for (int k0 = 0; k0 < 4; ++k0) {
      bf16x8 bfr = *(const bf16x8*)(xb + (size_t)(t * 16 + l16) * 128 + k0 * 32 + quad * 8);
      acc = __builtin_amdgcn_mfma_f32_16x16x32_bf16(a[k0], bfr, acc, 0, 0, 0);
    }
    float sj = ssq[t * 16 + l16];
    float cvld = svld[t * 16 + l16];
#pragma unroll
    for (int r = 0; r < 4; ++r) {
      float cv = sqrtf(fmaxf(si[r] + sj - 2.0f * acc[r], 1e-12f));
      float yv = (cv - m) * rsc;
      yv = yv >= 0.0f ? yv : 9.0f * yv;
      y[t][r] = yv * rv[r] * cvld;
    }
  }
  // row softmax -> bf16 co tile in LDS
#pragma unroll
  for (int r = 0; r < 4; ++r) {
    float mx = y[0][r];
#pragma unroll
    for (int t = 1; t < 16; ++t) mx = fmaxf(mx, y[t][r]);
#pragma unroll
    for (int off = 1; off <= 8; off <<= 1) mx = fmaxf(mx, __shfl_xor(mx, off));
    float s = 0.0f;
#pragma unroll
    for (int t = 0; t < 16; ++t) { y[t][r] = expf(y[t][r] - mx); s += y[t][r]; }
#pragma unroll
    for (int off = 1; off <= 8; off <<= 1) s += __shfl_xor(s, off);
    float inv = 1.0f / s;
#pragma unroll
    for (int t = 0; t < 16; ++t)
      cot[quad * 4 + r][t * 16 + l16] =
          __bfloat16_as_ushort(__float2bfloat16(y[t][r] * inv));
  }
  __syncthreads();
  // AV: A = co tile from LDS (A[m=l16][k=quad*8+j]), B = xT
  bf16x8 a2[8];
#pragma unroll
  for (int k0 = 0; k0 < 8; ++k0)
    a2[k0] = *(const bf16x8*)&cot[l16][k0 * 32 + quad * 8];
  const __bf16* xbT = (const __bf16*)xT + (size_t)bh * 128 * 256;
  float mv = stats[h], rvs = stats[6 + h];
  float rm = rvs * mv;
  size_t vbase = ((size_t)(b * 256 + I + quad * 4)) * 768 + h * 128;
#pragma unroll
  for (int jt = 0; jt < 8; ++jt) {
    int ch = jt * 16 + l16;
    const __bf16* brow = xbT + (size_t)ch * 256;
    f32x4 vacc = {0.0f, 0.0f, 0.0f, 0.0f};
#pragma unroll
    for (int k0 = 0; k0 < 8; ++k0) {
      bf16x8 bfr = *(const bf16x8*)(brow + k0 * 32 + quad * 8);
      vacc = __builtin_amdgcn_mfma_f32_16x16x32_bf16(a2[k0], bfr, vacc, 0, 0, 0);
    }
#pragma unroll
    for (int r = 0; r < 4; ++r) {
      float ov = rvs * vacc[r] - rm;
      vc16[vbase + (size_t)r * 768 + ch] = __bfloat16_as_ushort(__float2bfloat16(ov));
    }
  }
}

// ---------------- K56: logits + per-batch class sums + final softmax -> out ----------------
// 1 block per batch b (16 blocks x 256 thr).
__global__ __launch_bounds__(256) void k56_final(const unsigned short* __restrict__ vc16,
    const float* __restrict__ fcW, const float* __restrict__ fcb,
    float* __restrict__ out) {
  int b = blockIdx.x;
  int tid = threadIdx.x, w = tid >> 6, lane = tid & 63;
  int quad = lane >> 4, l16 = lane & 15;
  int c1c = (l16 < 5) ? (16 + l16) : 20;
  const __bf16* vb = (const __bf16*)vc16;
  const float* w0 = fcW + (size_t)l16 * 768;
  const float* w1 = fcW + (size_t)c1c * 768;
  float bias0 = fcb[l16];
  float bias1 = (l16 < 5) ? fcb[16 + l16] : 0.0f;
  float p0s = 0.0f, p1s = 0.0f;
  for (int g = 0; g < 4; ++g) {
    int tok0 = b * 256 + g * 64 + w * 16;
    f32x4 ac0 = {0.0f, 0.0f, 0.0f, 0.0f}, ac1 = {0.0f, 0.0f, 0.0f, 0.0f};
#pragma unroll
    for (int k0 = 0; k0 < 24; ++k0) {
      int ko = k0 * 32 + quad * 8;
      bf16x8 af = *(const bf16x8*)(vb + (size_t)(tok0 + l16) * 768 + ko);
      bf16x8 b0, b1;
#pragma unroll
      for (int e = 0; e < 8; ++e) {
        b0[e] = (__bf16)w0[ko + e];
        b1[e] = (__bf16)w1[ko + e];
      }
      ac0 = __builtin_amdgcn_mfma_f32_16x16x32_bf16(af, b0, ac0, 0, 0, 0);
      ac1 = __builtin_amdgcn_mfma_f32_16x16x32_bf16(af, b1, ac1, 0, 0, 0);
    }
#pragma unroll
    for (int r = 0; r < 4; ++r) {
      float lg0 = ac0[r] + bias0;
      float lg1 = (l16 < 5) ? (ac1[r] + bias1) : -1e30f;
      float mx = fmaxf(lg0, lg1);
#pragma unroll
      for (int off = 1; off <= 8; off <<= 1) mx = fmaxf(mx, __shfl_xor(mx, off));
      float e0 = expf(lg0 - mx), e1 = expf(lg1 - mx);
      float s = e0 + e1;
#pragma unroll
      for (int off = 1; off <= 8; off <<= 1) s += __shfl_xor(s, off);
      float inv = 1.0f / s;
      p0s += e0 * inv;
      p1s += e1 * inv;
    }
  }
  p0s += __shfl_xor(p0s, 16); p0s += __shfl_xor(p0s, 32);
  p1s += __shfl_xor(p1s, 16); p1s += __shfl_xor(p1s, 32);
  __shared__ float sacc[4][21];
  __shared__ float tot[21];
  if (quad == 0) sacc[w][l16] = p0s;
  if (quad == 1 && l16 < 5) sacc[w][16 + l16] = p1s;
  __syncthreads();
  if (tid < 21) tot[tid] = sacc[0][tid] + sacc[1][tid] + sacc[2][tid] + sacc[3][tid];
  __syncthreads();
  if (tid == 0) {
    float mx = -1e30f;
    for (int c = 0; c < 20; ++c) mx = fmaxf(mx, tot[c]);
    float e[20], s = 0.0f;
    for (int c = 0; c < 20; ++c) { e[c] = expf(tot[c] - mx); s += e[c]; }
    float inv = 1.0f / s;
    for (int c = 0; c < 20; ++c) out[b * 20 + c] = e[c] * inv;
  }
}

extern "C" void kernel_launch(void* const* d_in, const int* in_sizes, int n_in,
                              void* d_out, int out_size, void* d_ws, size_t ws_size,
                              hipStream_t stream) {
  const int*   tids = (const int*)d_in[0];
  const float* TF   = (const float*)d_in[1];
  const float* DF   = (const float*)d_in[2];
  const float* emb  = (const float*)d_in[3];
  const float* fcW  = (const float*)d_in[4];
  const float* fcb  = (const float*)d_in[5];
  // d_in[6]=weiW, d_in[7]=weib: dead code (cw branch is provably all-ones)
  float* out = (float*)d_out;
  float* ws  = (float*)d_ws;
  unsigned short* xh = (unsigned short*)(ws + OFF_XH);
  unsigned short* xT = (unsigned short*)(ws + OFF_XT);
  unsigned short* vc = (unsigned short*)(ws + OFF_VC);
  float* sq    = ws + OFF_SQ;
  float* ths   = ws + OFF_THS;
  float* part  = ws + OFF_PART;
  float* stats = ws + OFF_STAT;

  k1_gather<<<1536, 256, 0, stream>>>(tids, TF, DF, emb, xh, xT, sq, ths);
  k2_stats<<<dim3(16, 96), 64, 0, stream>>>(xh, sq, part);
  k3_stats<<<1, 384, 0, stream>>>(ths, sq, part, stats);
  k45_fused<<<dim3(16, 96), 64, 0, stream>>>(xh, xT, tids, sq, stats, vc);
  k56_final<<<16, 256, 0, stream>>>(vc, fcW, fcb, out);
}

// Round 8
// 213.955 us; speedup vs baseline: 1.0762x; 1.0762x over previous
//
#include <hip/hip_runtime.h>
#include <hip/hip_bf16.h>
#include <math.h>

// ws layout (float slots)
#define OFF_XH   0UL         // bf16 x  (bh, l, 128)
#define OFF_XT   1572864UL   // bf16 x^T (bh, 128, l) token-paired u32
#define OFF_VC   3145728UL   // bf16 vc (b, l, 768)
#define OFF_SQ   4718592UL   // fp32 per-(bh,l) sumsq          (24576)
#define OFF_THS  4743168UL   // fp32 per-(bh,l) sum            (24576)
#define OFF_PART 4767744UL   // fp32 dist partials 96*16*4*2   (12288)
#define OFF_STAT 4780032UL   // 24
#define OFF_ACC  4780056UL   // 336
#define OFF_FCWB 4780392UL   // bf16 fcW cast, 21*768 (8064 slots)

typedef __attribute__((ext_vector_type(8))) __bf16 bf16x8;
typedef __attribute__((ext_vector_type(4))) float f32x4;
typedef __attribute__((ext_vector_type(8))) unsigned short u16x8;

// ---------------- K1: gather+scale -> xh AND xT + per-token stats ----------------
__global__ __launch_bounds__(256) void k1_gather(const int* __restrict__ tids,
    const float* __restrict__ TF, const float* __restrict__ DF,
    const float* __restrict__ emb, unsigned short* __restrict__ xh,
    unsigned short* __restrict__ xT, float* __restrict__ sq, float* __restrict__ ths) {
  int bh = blockIdx.x >> 4, tg = blockIdx.x & 15;
  int b = bh / 6, h = bh % 6;
  int T0 = tg * 16;
  int tid = threadIdx.x;
  __shared__ float swgt[16];
  __shared__ int stid[16];
  __shared__ unsigned short tT[128][18];
  if (tid < 16) {
    int tok = b * 256 + T0 + tid;
    stid[tid] = tids[tok];
    swgt[tid] = fminf(TF[tok], 20.0f) * log1pf(1.0f / DF[tok]);
  }
  __syncthreads();
  int r = tid >> 4, c8 = (tid & 15) * 8;
  const float* er = emb + (size_t)stid[r] * 768 + h * 128 + c8;
  float wgt = swgt[r];
  float4 e0 = *(const float4*)er;
  float4 e1 = *(const float4*)(er + 4);
  float f[8] = {e0.x, e0.y, e0.z, e0.w, e1.x, e1.y, e1.z, e1.w};
  float s1 = 0.0f, s2 = 0.0f;
  u16x8 pk;
#pragma unroll
  for (int e = 0; e < 8; ++e) {
    __hip_bfloat16 hb = __float2bfloat16(f[e] * wgt);
    float g = __bfloat162float(hb);
    s1 += g; s2 += g * g;
    pk[e] = __bfloat16_as_ushort(hb);
  }
  *(u16x8*)(xh + ((size_t)(bh * 256 + T0 + r)) * 128 + c8) = pk;
  s1 += __shfl_down(s1, 8); s1 += __shfl_down(s1, 4);
  s1 += __shfl_down(s1, 2); s1 += __shfl_down(s1, 1);
  s2 += __shfl_down(s2, 8); s2 += __shfl_down(s2, 4);
  s2 += __shfl_down(s2, 2); s2 += __shfl_down(s2, 1);
  if ((tid & 15) == 0) {
    ths[bh * 256 + T0 + r] = s1;
    sq[bh * 256 + T0 + r]  = s2;
  }
#pragma unroll
  for (int j = 0; j < 8; ++j) tT[c8 + j][r] = pk[j];
  __syncthreads();
  int ch = tid >> 1, half = tid & 1;
  unsigned int* xo = (unsigned int*)xT + ((size_t)(bh * 128 + ch)) * 128 + tg * 8 + half * 4;
#pragma unroll
  for (int k = 0; k < 4; ++k)
    xo[k] = *(const unsigned int*)&tT[ch][(half * 4 + k) * 2];
}

// ---------------- K2: distance-stat partials. 4 waves/block, wave w -> 4 col-tiles ----------------
__global__ __launch_bounds__(256) void k2_stats(const unsigned short* __restrict__ xh,
    const float* __restrict__ sq, float* __restrict__ part) {
  int p = blockIdx.x, bh = blockIdx.y;
  int tid = threadIdx.x, w = tid >> 6, lane = tid & 63;
  int quad = lane >> 4, l16 = lane & 15;
  int I = p * 16;
  const __bf16* xb = (const __bf16*)xh + (size_t)bh * 256 * 128;
  bf16x8 a[4];
#pragma unroll
  for (int k0 = 0; k0 < 4; ++k0)
    a[k0] = *(const bf16x8*)(xb + (size_t)(I + l16) * 128 + k0 * 32 + quad * 8);
  const float* sqh = sq + (size_t)bh * 256;
  float si[4];
#pragma unroll
  for (int r = 0; r < 4; ++r) si[r] = sqh[I + quad * 4 + r];
  float ls1 = 0.0f, ls2 = 0.0f;
#pragma unroll
  for (int tl = 0; tl < 4; ++tl) {
    int t = w * 4 + tl;
    f32x4 acc = {0.0f, 0.0f, 0.0f, 0.0f};
#pragma unroll
    for (int k0 = 0; k0 < 4; ++k0) {
      bf16x8 bfr = *(const bf16x8*)(xb + (size_t)(t * 16 + l16) * 128 + k0 * 32 + quad * 8);
      acc = __builtin_amdgcn_mfma_f32_16x16x32_bf16(a[k0], bfr, acc, 0, 0, 0);
    }
    float sj = sqh[t * 16 + l16];
#pragma unroll
    for (int r = 0; r < 4; ++r) {
      float cv = sqrtf(fmaxf(si[r] + sj - 2.0f * acc[r], 1e-12f));
      ls1 += cv; ls2 += cv * cv;
    }
  }
#pragma unroll
  for (int off = 32; off >= 1; off >>= 1) {
    ls1 += __shfl_down(ls1, off);
    ls2 += __shfl_down(ls2, off);
  }
  if (lane == 0) {
    part[(((size_t)bh * 16 + p) * 4 + w) * 2 + 0] = ls1;
    part[(((size_t)bh * 16 + p) * 4 + w) * 2 + 1] = ls2;
  }
}

// ---------------- K3: finalize BN stats + zero acc + cast fcW -> bf16 ----------------
__global__ __launch_bounds__(384) void k3_stats(const float* __restrict__ ths,
    const float* __restrict__ sq, const float* __restrict__ part,
    const float* __restrict__ fcW, float* __restrict__ stats,
    float* __restrict__ acc, unsigned short* __restrict__ fcWb) {
  int h = threadIdx.x >> 6, lane = threadIdx.x & 63;
  float s1 = 0.0f, s2 = 0.0f;
  for (int m = 0; m < 64; ++m) {
    int f = m * 64 + lane;
    int bb = f >> 8, l = f & 255;
    size_t idx = ((size_t)(bb * 6 + h)) * 256 + l;
    s1 += ths[idx]; s2 += sq[idx];
  }
#pragma unroll
  for (int off = 32; off >= 1; off >>= 1) {
    s1 += __shfl_down(s1, off);
    s2 += __shfl_down(s2, off);
  }
  if (lane == 0) {
    float cnt = 524288.0f;               // B*L*dh
    float mean = s1 / cnt;
    float var = s2 / cnt - mean * mean;
    stats[h] = mean;
    stats[6 + h] = rsqrtf(var + 1e-5f);
  }
  float c1 = 0.0f, c2 = 0.0f;
#pragma unroll
  for (int t = 0; t < 16; ++t) {
    int e = lane + 64 * t;               // 0..1023 = 16 b x 16 p x 4 w
    int bb = e >> 6, rest = e & 63, pp = rest >> 2, ww = rest & 3;
    size_t pidx = ((((size_t)(bb * 6 + h)) * 16 + pp) * 4 + ww) * 2;
    c1 += part[pidx]; c2 += part[pidx + 1];
  }
#pragma unroll
  for (int off = 32; off >= 1; off >>= 1) {
    c1 += __shfl_down(c1, off);
    c2 += __shfl_down(c2, off);
  }
  if (lane == 0) {
    float cnt = 1048576.0f;              // B*L*L
    float mean = c1 / cnt;
    float var = c2 / cnt - mean * mean;
    stats[12 + h] = mean;
    stats[18 + h] = rsqrtf(var + 1e-5f);
  }
  if (threadIdx.x < 336) acc[threadIdx.x] = 0.0f;
  for (int idx = threadIdx.x; idx < 21 * 768; idx += 384)
    fcWb[idx] = __bfloat16_as_ushort(__float2bfloat16(fcW[idx]));
}

// ---------------- K45: dist+bn+leaky+mask+softmax (LDS co) + AV. 4 waves/tile ----------------
// Wave w: dist cols [64w,64w+64); softmax partials via LDS; AV ch-tiles {2w,2w+1}.
__global__ __launch_bounds__(256, 4) void k45_fused(const unsigned short* __restrict__ xh,
    const unsigned short* __restrict__ xT, const int* __restrict__ tids,
    const float* __restrict__ sq, const float* __restrict__ stats,
    unsigned short* __restrict__ vc16) {
  int p = blockIdx.x, bh = blockIdx.y;
  int b = bh / 6, h = bh % 6;
  int tid = threadIdx.x, w = tid >> 6, lane = tid & 63;
  int quad = lane >> 4, l16 = lane & 15;
  int I = p * 16;
  __shared__ float svld[256];
  __shared__ float ssq[256];
  __shared__ unsigned short cot[16][264];
  __shared__ float smax[16][4];
  __shared__ float ssum[16][4];
  svld[tid] = (tids[b * 256 + tid] != 0) ? 1.0f : 0.0f;
  ssq[tid] = sq[(size_t)bh * 256 + tid];
  const __bf16* xb = (const __bf16*)xh + (size_t)bh * 256 * 128;
  bf16x8 a[4];
#pragma unroll
  for (int k0 = 0; k0 < 4; ++k0)
    a[k0] = *(const bf16x8*)(xb + (size_t)(I + l16) * 128 + k0 * 32 + quad * 8);
  __syncthreads();
  float m = stats[12 + h], rsc = stats[18 + h];
  float rv[4], si[4];
#pragma unroll
  for (int r = 0; r < 4; ++r) {
    rv[r] = svld[I + quad * 4 + r];
    si[r] = ssq[I + quad * 4 + r];
  }
  float y[4][4];
#pragma unroll
  for (int tl = 0; tl < 4; ++tl) {
    int t = w * 4 + tl;
    f32x4 acc = {0.0f, 0.0f, 0.0f, 0.0f};
#pragma unroll
    for (int k0 = 0; k0 < 4; ++k0) {
      bf16x8 bfr = *(const bf16x8*)(xb + (size_t)(t * 16 + l16) * 128 + k0 * 32 + quad * 8);
      acc = __builtin_amdgcn_mfma_f32_16x16x32_bf16(a[k0], bfr, acc, 0, 0, 0);
    }
    float sj = ssq[t * 16 + l16];
    float cvld = svld[t * 16 + l16];
#pragma unroll
    for (int r = 0; r < 4; ++r) {
      float cv = sqrtf(fmaxf(si[r] + sj - 2.0f * acc[r], 1e-12f));
      float yv = (cv - m) * rsc;
      yv = yv >= 0.0f ? yv : 9.0f * yv;
      y[tl][r] = yv * rv[r] * cvld;
    }
  }
  // softmax stage 1: per-(row,wave) max
#pragma unroll
  for (int r = 0; r < 4; ++r) {
    float mx = fmaxf(fmaxf(y[0][r], y[1][r]), fmaxf(y[2][r], y[3][r]));
#pragma unroll
    for (int off = 1; off <= 8; off <<= 1) mx = fmaxf(mx, __shfl_xor(mx, off));
    if (l16 == 0) smax[quad * 4 + r][w] = mx;
  }
  __syncthreads();
  // stage 2: global max, exp, per-(row,wave) sum
  float gmx[4];
#pragma unroll
  for (int r = 0; r < 4; ++r) {
    int row = quad * 4 + r;
    gmx[r] = fmaxf(fmaxf(smax[row][0], smax[row][1]), fmaxf(smax[row][2], smax[row][3]));
    float s = 0.0f;
#pragma unroll
    for (int tl = 0; tl < 4; ++tl) { y[tl][r] = expf(y[tl][r] - gmx[r]); s += y[tl][r]; }
#pragma unroll
    for (int off = 1; off <= 8; off <<= 1) s += __shfl_xor(s, off);
    if (l16 == 0) ssum[row][w] = s;
  }
  __syncthreads();
  // stage 3: normalize, write bf16 co tile slice
#pragma unroll
  for (int r = 0; r < 4; ++r) {
    int row = quad * 4 + r;
    float gs = ssum[row][0] + ssum[row][1] + ssum[row][2] + ssum[row][3];
    float inv = 1.0f / gs;
#pragma unroll
    for (int tl = 0; tl < 4; ++tl)
      cot[row][w * 64 + tl * 16 + l16] =
          __bfloat16_as_ushort(__float2bfloat16(y[tl][r] * inv));
  }
  __syncthreads();
  // AV: A = co tile from LDS, B = xT; wave w handles ch-tiles {2w, 2w+1}
  bf16x8 a2[8];
#pragma unroll
  for (int k0 = 0; k0 < 8; ++k0)
    a2[k0] = *(const bf16x8*)&cot[l16][k0 * 32 + quad * 8];
  const __bf16* xbT = (const __bf16*)xT + (size_t)bh * 128 * 256;
  float mv = stats[h], rvs = stats[6 + h];
  float rm = rvs * mv;
  size_t vbase = ((size_t)(b * 256 + I + quad * 4)) * 768 + h * 128;
#pragma unroll
  for (int jl = 0; jl < 2; ++jl) {
    int ch = (w * 2 + jl) * 16 + l16;
    const __bf16* brow = xbT + (size_t)ch * 256;
    f32x4 vacc = {0.0f, 0.0f, 0.0f, 0.0f};
#pragma unroll
    for (int k0 = 0; k0 < 8; ++k0) {
      bf16x8 bfr = *(const bf16x8*)(brow + k0 * 32 + quad * 8);
      vacc = __builtin_amdgcn_mfma_f32_16x16x32_bf16(a2[k0], bfr, vacc, 0, 0, 0);
    }
#pragma unroll
    for (int r = 0; r < 4; ++r) {
      float ov = rvs * vacc[r] - rm;
      vc16[vbase + (size_t)r * 768 + ch] = __bfloat16_as_ushort(__float2bfloat16(ov));
    }
  }
}

// ---------------- K5b: logits via MFMA + 21-softmax + per-batch accumulate ----------------
// 64 blocks = (b, quarter); each wave 16 tokens; bf16 weights preloaded.
__global__ __launch_bounds__(256) void k5b_lgts(const unsigned short* __restrict__ vc16,
    const unsigned short* __restrict__ fcWb, const float* __restrict__ fcb,
    float* __restrict__ acc) {
  int b = blockIdx.x >> 2, qa = blockIdx.x & 3;
  int tid = threadIdx.x, w = tid >> 6, lane = tid & 63;
  int quad = lane >> 4, l16 = lane & 15;
  int tok0 = b * 256 + qa * 64 + w * 16;
  int c1c = (l16 < 5) ? (16 + l16) : 20;
  const __bf16* vb = (const __bf16*)vc16;
  const __bf16* w0 = (const __bf16*)fcWb + (size_t)l16 * 768;
  const __bf16* w1 = (const __bf16*)fcWb + (size_t)c1c * 768;
  f32x4 ac0 = {0.0f, 0.0f, 0.0f, 0.0f}, ac1 = {0.0f, 0.0f, 0.0f, 0.0f};
#pragma unroll
  for (int k0 = 0; k0 < 24; ++k0) {
    int ko = k0 * 32 + quad * 8;
    bf16x8 af = *(const bf16x8*)(vb + (size_t)(tok0 + l16) * 768 + ko);
    bf16x8 b0 = *(const bf16x8*)(w0 + ko);
    bf16x8 b1 = *(const bf16x8*)(w1 + ko);
    ac0 = __builtin_amdgcn_mfma_f32_16x16x32_bf16(af, b0, ac0, 0, 0, 0);
    ac1 = __builtin_amdgcn_mfma_f32_16x16x32_bf16(af, b1, ac1, 0, 0, 0);
  }
  float bias0 = fcb[l16];
  float bias1 = (l16 < 5) ? fcb[16 + l16] : 0.0f;
  float p0s = 0.0f, p1s = 0.0f;
#pragma unroll
  for (int r = 0; r < 4; ++r) {
    float lg0 = ac0[r] + bias0;
    float lg1 = (l16 < 5) ? (ac1[r] + bias1) : -1e30f;
    float mx = fmaxf(lg0, lg1);
#pragma unroll
    for (int off = 1; off <= 8; off <<= 1) mx = fmaxf(mx, __shfl_xor(mx, off));
    float e0 = expf(lg0 - mx), e1 = expf(lg1 - mx);
    float s = e0 + e1;
#pragma unroll
    for (int off = 1; off <= 8; off <<= 1) s += __shfl_xor(s, off);
    float inv = 1.0f / s;
    p0s += e0 * inv;
    p1s += e1 * inv;
  }
  p0s += __shfl_xor(p0s, 16); p0s += __shfl_xor(p0s, 32);
  p1s += __shfl_xor(p1s, 16); p1s += __shfl_xor(p1s, 32);
  __shared__ float sacc[4][21];
  if (quad == 0) sacc[w][l16] = p0s;
  if (quad == 1 && l16 < 5) sacc[w][16 + l16] = p1s;
  __syncthreads();
  if (tid < 21) {
    float s = sacc[0][tid] + sacc[1][tid] + sacc[2][tid] + sacc[3][tid];
    atomicAdd(&acc[b * 21 + tid], s);
  }
}

// ---------------- K6: final softmax over first 20 classes ----------------
__global__ __launch_bounds__(64) void k6_final(const float* __restrict__ acc,
                                               float* __restrict__ out) {
  int b = threadIdx.x;
  if (b < 16) {
    float mx = -1e30f;
    for (int c = 0; c < 20; ++c) mx = fmaxf(mx, acc[b * 21 + c]);
    float e[20], s = 0.0f;
    for (int c = 0; c < 20; ++c) { e[c] = expf(acc[b * 21 + c] - mx); s += e[c]; }
    float inv = 1.0f / s;
    for (int c = 0; c < 20; ++c) out[b * 20 + c] = e[c] * inv;
  }
}

extern "C" void kernel_launch(void* const* d_in, const int* in_sizes, int n_in,
                              void* d_out, int out_size, void* d_ws, size_t ws_size,
                              hipStream_t stream) {
  const int*   tids = (const int*)d_in[0];
  const float* TF   = (const float*)d_in[1];
  const float* DF   = (const float*)d_in[2];
  const float* emb  = (const float*)d_in[3];
  const float* fcW  = (const float*)d_in[4];
  const float* fcb  = (const float*)d_in[5];
  // d_in[6]=weiW, d_in[7]=weib: dead code (cw branch is provably all-ones)
  float* out = (float*)d_out;
  float* ws  = (float*)d_ws;
  unsigned short* xh   = (unsigned short*)(ws + OFF_XH);
  unsigned short* xT   = (unsigned short*)(ws + OFF_XT);
  unsigned short* vc   = (unsigned short*)(ws + OFF_VC);
  unsigned short* fcWb = (unsigned short*)(ws + OFF_FCWB);
  float* sq    = ws + OFF_SQ;
  float* ths   = ws + OFF_THS;
  float* part  = ws + OFF_PART;
  float* stats = ws + OFF_STAT;
  float* acc   = ws + OFF_ACC;

  k1_gather<<<1536, 256, 0, stream>>>(tids, TF, DF, emb, xh, xT, sq, ths);
  k2_stats<<<dim3(16, 96), 256, 0, stream>>>(xh, sq, part);
  k3_stats<<<1, 384, 0, stream>>>(ths, sq, part, fcW, stats, acc, fcWb);
  k45_fused<<<dim3(16, 96), 256, 0, stream>>>(xh, xT, tids, sq, stats, vc);
  k5b_lgts<<<64, 256, 0, stream>>>(vc, fcWb, fcb, acc);
  k6_final<<<1, 64, 0, stream>>>(acc, out);
}